// Round 5
// baseline (167.578 us; speedup 1.0000x reference)
//
#include <hip/hip_runtime.h>

// out[i] = sum_{j=0..9} in[10*i + j] * (j+1)/55   (stride==d==10 -> windows tile T exactly)
//
// R5 = R4 with the nontemporal-store type fixed (native clang vector, not HIP_vector_type).
//  - each thread: one chunk of 20 float4 = 80 floats = 8 windows -> 8 outputs (2 x 16B stores)
//  - all 20 independent loads issue up front; compiler drains with progressive vmcnt
//  - no loop, no LDS, no barriers
//  - in: 153,600,000 floats = 1,920,000 chunks = 7500 blocks x 256 threads (exact, no tail)

typedef float floatx4 __attribute__((ext_vector_type(4)));

__global__ __launch_bounds__(256) void ts_decaylinear_kernel(
    const float4* __restrict__ in4, floatx4* __restrict__ out4) {

    const float w0 = 1.0f / 55.0f, w1 = 2.0f / 55.0f, w2 = 3.0f / 55.0f,
                w3 = 4.0f / 55.0f, w4 = 5.0f / 55.0f, w5 = 6.0f / 55.0f,
                w6 = 7.0f / 55.0f, w7 = 8.0f / 55.0f, w8 = 9.0f / 55.0f,
                w9 = 10.0f / 55.0f;

    const long long t = (long long)blockIdx.x * blockDim.x + threadIdx.x;
    const float4* __restrict__ p = in4 + t * 20;

    float4 a0  = p[0],  a1  = p[1],  a2  = p[2],  a3  = p[3],  a4  = p[4];
    float4 a5  = p[5],  a6  = p[6],  a7  = p[7],  a8  = p[8],  a9  = p[9];
    float4 a10 = p[10], a11 = p[11], a12 = p[12], a13 = p[13], a14 = p[14];
    float4 a15 = p[15], a16 = p[16], a17 = p[17], a18 = p[18], a19 = p[19];

    floatx4 r0, r1;

    r0.x = a0.x * w0 + a0.y * w1 + a0.z * w2 + a0.w * w3
         + a1.x * w4 + a1.y * w5 + a1.z * w6 + a1.w * w7
         + a2.x * w8 + a2.y * w9;
    r0.y = a2.z * w0 + a2.w * w1
         + a3.x * w2 + a3.y * w3 + a3.z * w4 + a3.w * w5
         + a4.x * w6 + a4.y * w7 + a4.z * w8 + a4.w * w9;

    r0.z = a5.x * w0 + a5.y * w1 + a5.z * w2 + a5.w * w3
         + a6.x * w4 + a6.y * w5 + a6.z * w6 + a6.w * w7
         + a7.x * w8 + a7.y * w9;
    r0.w = a7.z * w0 + a7.w * w1
         + a8.x * w2 + a8.y * w3 + a8.z * w4 + a8.w * w5
         + a9.x * w6 + a9.y * w7 + a9.z * w8 + a9.w * w9;

    r1.x = a10.x * w0 + a10.y * w1 + a10.z * w2 + a10.w * w3
         + a11.x * w4 + a11.y * w5 + a11.z * w6 + a11.w * w7
         + a12.x * w8 + a12.y * w9;
    r1.y = a12.z * w0 + a12.w * w1
         + a13.x * w2 + a13.y * w3 + a13.z * w4 + a13.w * w5
         + a14.x * w6 + a14.y * w7 + a14.z * w8 + a14.w * w9;

    r1.z = a15.x * w0 + a15.y * w1 + a15.z * w2 + a15.w * w3
         + a16.x * w4 + a16.y * w5 + a16.z * w6 + a16.w * w7
         + a17.x * w8 + a17.y * w9;
    r1.w = a17.z * w0 + a17.w * w1
         + a18.x * w2 + a18.y * w3 + a18.z * w4 + a18.w * w5
         + a19.x * w6 + a19.y * w7 + a19.z * w8 + a19.w * w9;

    __builtin_nontemporal_store(r0, &out4[t * 2]);
    __builtin_nontemporal_store(r1, &out4[t * 2 + 1]);
}

extern "C" void kernel_launch(void* const* d_in, const int* in_sizes, int n_in,
                              void* d_out, int out_size, void* d_ws, size_t ws_size,
                              hipStream_t stream) {
    const float4* in4 = (const float4*)d_in[0];
    floatx4* out4 = (floatx4*)d_out;

    // 153,600,000 floats / 80 floats-per-thread = 1,920,000 threads = 7500 x 256 (exact)
    long long n_threads = (long long)in_sizes[0] / 80;
    int grid = (int)((n_threads + 255) / 256);

    ts_decaylinear_kernel<<<grid, 256, 0, stream>>>(in4, out4);
}